// Round 9
// baseline (643.536 us; speedup 1.0000x reference)
//
#include <hip/hip_runtime.h>
#include <hip/hip_bf16.h>
#include <math.h>

// Problem constants (B=4, 128x128 grid, DIM=256, 8 heads x 64)
#define NB 4
#define NY 128
#define NX 128
#define DIM 256
#define NH 8
#define DH_ 64
#define HDIM 512   // NH*DH
#define HID 1024
#define NPOS (NB*NY*NX)   // 65536

typedef __hip_bfloat16 bf16_t;
typedef __attribute__((ext_vector_type(8))) short short8;   // 8 bf16 = 1 MFMA A/B frag
typedef __attribute__((ext_vector_type(4))) float f32x4;    // MFMA C/D frag

__device__ __forceinline__ float b2f(bf16_t x){ return __bfloat162float(x); }
__device__ __forceinline__ bf16_t f2b(float x){ return __float2bfloat16(x); }
__device__ __forceinline__ short f2s(float x){ bf16_t h = __float2bfloat16(x); return *reinterpret_cast<short*>(&h); }
__device__ __forceinline__ float s2f(short x){ bf16_t h = *reinterpret_cast<bf16_t*>(&x); return __bfloat162float(h); }

// MFMA fragment layout (gfx950, verified):
//  A[m][k]: m = lane&15, k = (lane>>4)*8 + j
//  B[k][n]: n = lane&15, k = (lane>>4)*8 + j
//  D[row][col]: col = lane&15, row = (lane>>4)*4 + reg

// gelu tanh-approx: 0.5x(1+tanh(t)) == x*sigmoid(2t); __expf maps to v_exp_f32.
__device__ __forceinline__ float gelu_tanh(float x){
  float z = 1.5957691216057308f*(x + 0.044715f*x*x*x);
  return x / (1.0f + __expf(-z));
}

// ---------------------------------------------------------------- weight pack, ALL weights in one launch
struct PackArgs {
  const float* src[12];
  short* dst[12];
  int K[12];
  int N[12];
  int boff[12];    // starting block of each weight
};
__global__ void __launch_bounds__(256) k_pack_all(PackArgs pa){
  int idx = 0;
  #pragma unroll
  for (int j=1;j<12;j++) if ((int)blockIdx.x >= pa.boff[j]) idx = j;
  int tid = ((int)blockIdx.x - pa.boff[idx])*256 + threadIdx.x;   // < K*N/8
  const float* W = pa.src[idx];
  short* out = pa.dst[idx];
  int N = pa.N[idx];
  int lane = tid & 63;
  int rem = tid >> 6;
  int ntiles = N >> 4;
  int nt = rem % ntiles, kb = rem / ntiles;
  int n = nt*16 + (lane & 15);
  int k0 = kb*32 + (lane>>4)*8;
  short8 v;
  #pragma unroll
  for (int j=0;j<8;j++) v[j] = f2s(W[(size_t)(k0+j)*N + n]);
  *(short8*)&out[(size_t)tid*8] = v;
}

// ---------------------------------------------------------------- LN1 (f32 in -> bf16 un)
__global__ void __launch_bounds__(256) k_ln1(const float* __restrict__ u,
    const float* __restrict__ g, const float* __restrict__ b,
    bf16_t* __restrict__ un){
  int wave = threadIdx.x >> 6, lane = threadIdx.x & 63;
  size_t row = (size_t)blockIdx.x*4 + wave;
  const float* x = u + row*DIM;
  float v[4]; float s=0.f, ss=0.f;
  #pragma unroll
  for (int j=0;j<4;j++){ float t = x[lane + j*64]; v[j]=t; s+=t; ss+=t*t; }
  #pragma unroll
  for (int off=32;off>0;off>>=1){ s += __shfl_down(s,off,64); ss += __shfl_down(ss,off,64); }
  s = __shfl(s,0,64); ss = __shfl(ss,0,64);
  float m = s*(1.0f/DIM);
  float var = ss*(1.0f/DIM) - m*m;
  float r = rsqrtf(var + 1e-5f);
  bf16_t* o = un + row*DIM;
  #pragma unroll
  for (int j=0;j<4;j++){
    int f = lane + j*64;
    o[f] = f2b((v[j]-m)*r*g[f] + b[f]);
  }
}

// ---------------------------------------------------------------- pooling (bf16 un -> f32)
// 1024 threads: 4-way split of the 128-long reduction (serial chain 128->32)
__global__ void __launch_bounds__(1024) k_pool_y(const bf16_t* __restrict__ un, float* __restrict__ pooly){
  int by = blockIdx.x;                       // b*NY + y
  int d = threadIdx.x & 255, xq = threadIdx.x >> 8;
  __shared__ float part[4][256];
  size_t base = (size_t)by*NX*DIM + d;
  float s = 0.f;
  int x0 = xq*32;
  for (int x=x0; x<x0+32; x++) s += b2f(un[base + (size_t)x*DIM]);
  part[xq][d] = s;
  __syncthreads();
  if (threadIdx.x < 256)
    pooly[(size_t)by*DIM + d] = (part[0][d]+part[1][d]+part[2][d]+part[3][d])*(1.0f/NX);
}
__global__ void __launch_bounds__(1024) k_pool_x(const bf16_t* __restrict__ un, float* __restrict__ poolx){
  int bb = blockIdx.x / NX, x = blockIdx.x % NX;
  int d = threadIdx.x & 255, yq = threadIdx.x >> 8;
  __shared__ float part[4][256];
  size_t base = ((size_t)bb*NY*NX + x)*DIM + d;
  float s = 0.f;
  int y0 = yq*32;
  for (int y=y0; y<y0+32; y++) s += b2f(un[base + (size_t)y*NX*DIM]);
  part[yq][d] = s;
  __syncthreads();
  if (threadIdx.x < 256)
    poolx[(size_t)blockIdx.x*DIM + d] = (part[0][d]+part[1][d]+part[2][d]+part[3][d])*(1.0f/NY);
}

// ---------------------------------------------------------------- MFMA GEMM, x/y chains fused via blockIdx.z
// C[M x N] = op(A[M x K] @ W + bias); grid = (M/64, N/256, 2), block 256.
#define GS_STRIDE 72
__global__ void __launch_bounds__(256) k_gemm2(const float* __restrict__ A0,
    const float* __restrict__ A1,
    const short* __restrict__ W0, const short* __restrict__ W1,
    const float* __restrict__ b0, const float* __restrict__ b1,
    float* __restrict__ C0, float* __restrict__ C1, int N, int K, int dogelu){
  const float* A  = blockIdx.z ? A1 : A0;
  const short* WP = blockIdx.z ? W1 : W0;
  const float* bias = blockIdx.z ? b1 : b0;
  float* C = blockIdx.z ? C1 : C0;
  __shared__ __align__(16) short As[64*GS_STRIDE];   // 9.2 KB
  int tid = threadIdx.x;
  int lane = tid & 63, w = tid >> 6;
  int am = lane & 15, aq = lane >> 4;
  int m0 = blockIdx.x*64;
  int nt0 = blockIdx.y*16;
  int ntiles = N >> 4;
  f32x4 o[4][4];
  #pragma unroll
  for (int mt=0;mt<4;mt++)
    #pragma unroll
    for (int nt=0;nt<4;nt++) o[mt][nt] = (f32x4){0.f,0.f,0.f,0.f};

  for (int kc=0; kc<K; kc+=64){
    #pragma unroll
    for (int it=0; it<4; it++){
      int q = tid + it*256;
      int r = q >> 4, c4 = q & 15;
      float4 v = *(const float4*)&A[(size_t)(m0+r)*K + kc + c4*4];
      ushort4 p;
      p.x = (ushort)f2s(v.x); p.y = (ushort)f2s(v.y);
      p.z = (ushort)f2s(v.z); p.w = (ushort)f2s(v.w);
      *(ushort4*)&As[r*GS_STRIDE + c4*4] = p;
    }
    __syncthreads();
    #pragma unroll
    for (int kb=0; kb<2; kb++){
      short8 a[4], bfr[4];
      #pragma unroll
      for (int mt=0;mt<4;mt++)
        a[mt] = *(const short8*)&As[(mt*16+am)*GS_STRIDE + kb*32 + aq*8];
      int kbg = (kc>>5) + kb;
      #pragma unroll
      for (int nt=0;nt<4;nt++){
        int ntg = nt0 + w*4 + nt;
        bfr[nt] = *(const short8*)&WP[(size_t)((kbg*ntiles + ntg)*64 + lane)*8];
      }
      #pragma unroll
      for (int mt=0;mt<4;mt++)
        #pragma unroll
        for (int nt=0;nt<4;nt++)
          o[mt][nt] = __builtin_amdgcn_mfma_f32_16x16x32_bf16(a[mt], bfr[nt], o[mt][nt], 0,0,0);
    }
    __syncthreads();
  }

  #pragma unroll
  for (int nt=0;nt<4;nt++){
    int col = (nt0 + w*4 + nt)*16 + am;
    float bv = bias ? bias[col] : 0.f;
    #pragma unroll
    for (int mt=0;mt<4;mt++){
      #pragma unroll
      for (int reg=0;reg<4;reg++){
        int row = m0 + mt*16 + aq*4 + reg;
        float val = o[mt][nt][reg] + bv;
        if (dogelu) val = gelu_tanh(val);
        C[(size_t)row*N + col] = val;
      }
    }
  }
}

// ---------------------------------------------------------------- RoPE split, y+x fused via blockIdx.y
__global__ void __launch_bounds__(256) k_rope2(const float* __restrict__ qky,
    const float* __restrict__ qkx,
    const float* __restrict__ csy, const float* __restrict__ sny,
    const float* __restrict__ csx, const float* __restrict__ snx,
    float* __restrict__ qy, float* __restrict__ ky,
    float* __restrict__ qx, float* __restrict__ kx){
  const float* qk = blockIdx.y ? qkx : qky;
  const float* cs = blockIdx.y ? csx : csy;
  const float* sn = blockIdx.y ? snx : sny;
  float* q = blockIdx.y ? qx : qy;
  float* k = blockIdx.y ? kx : ky;
  int idx = blockIdx.x*256 + threadIdx.x;
  int c = idx & 63;
  int h = (idx>>6) & 7;
  int p = (idx>>9) & 1;
  int n = (idx>>10) & 127;
  int bb = idx>>17;
  float t = qk[idx];
  float t2 = qk[(c<32) ? idx+32 : idx-32];
  if (c<32) t2 = -t2;
  float val = t*cs[n*64+c] + t2*sn[n*64+c];
  float* dst = p ? k : q;
  dst[(((size_t)bb*NH + h)*128 + n)*64 + c] = val;
}

// ---------------------------------------------------------------- attention matrix, y+x fused via blockIdx.y
__global__ void __launch_bounds__(128) k_attn2(const float* __restrict__ qy,
    const float* __restrict__ ky, bf16_t* __restrict__ ay,
    const float* __restrict__ qx, const float* __restrict__ kx,
    bf16_t* __restrict__ ax){
  const float* q = blockIdx.y ? qx : qy;
  const float* k = blockIdx.y ? kx : ky;
  bf16_t* attn = blockIdx.y ? ax : ay;
  int i = blockIdx.x & 127;
  int bh = blockIdx.x >> 7;
  __shared__ float qs[64];
  __shared__ float red[4];
  int tid = threadIdx.x;
  int wv = tid >> 6, lane = tid & 63;
  const float* qrow = q + ((size_t)bh*128 + i)*64;
  if (tid < 64) qs[tid] = qrow[tid];
  __syncthreads();
  const float* krow = k + ((size_t)bh*128 + tid)*64;
  float dot = 0.f;
  for (int c=0;c<64;c++) dot += qs[c]*krow[c];
  dot *= (1.0f/64.0f);
  float mx = dot;
  #pragma unroll
  for (int off=32;off>0;off>>=1) mx = fmaxf(mx, __shfl_xor(mx, off, 64));
  if (lane == 0) red[wv] = mx;
  __syncthreads();
  mx = fmaxf(red[0], red[1]);
  float e = __expf(dot - mx);
  float s = e;
  #pragma unroll
  for (int off=32;off>0;off>>=1) s += __shfl_xor(s, off, 64);
  if (lane == 0) red[2+wv] = s;
  __syncthreads();
  s = red[2] + red[3];
  attn[(size_t)blockIdx.x*128 + tid] = f2b(e/s);
}

// ---------------------------------------------------------------- MFMA phi1: V-proj + y-attention
// 512 threads = 8 waves, each owning 16 rows.
#define AST 136   // 128 + 8 shorts
#define UST 72    // 64 + 8 shorts
#define VST 136
__global__ void __launch_bounds__(512) k_phi1m(const bf16_t* __restrict__ un,
    const short* __restrict__ WvP, const bf16_t* __restrict__ attn,
    bf16_t* __restrict__ phi){
  int m  = blockIdx.x & (NX-1);
  int bh = blockIdx.x >> 7;
  int b  = bh >> 3, h = bh & 7;
  __shared__ __align__(16) short At[128*AST];   // 34.8 KB
  __shared__ __align__(16) short unc[128*UST];  // 18.4 KB
  __shared__ __align__(16) short Vt[64*VST];    // 17.4 KB  [c][y]
  int tid = threadIdx.x;
  int lane = tid & 63, w = tid >> 6;            // w in 0..7
  int am = lane & 15, aq = lane >> 4;

  // stage attn slice (bh): 128x128 bf16 -> At (read only in phase 2)
  {
    const ushort* ag = (const ushort*)attn + (size_t)bh*16384;
    #pragma unroll
    for (int it=0; it<8; it++){
      int q = tid + it*512;          // < 4096 ushort4
      int i = q >> 5, j4 = q & 31;
      *(ushort4*)&At[i*AST + j4*4] = *(const ushort4*)(ag + i*128 + j4*4);
    }
  }

  // ---- phase 1: V-projection (wave w owns y rows w*16..+15, all 64 c)
  f32x4 v[4];
  #pragma unroll
  for (int nt=0;nt<4;nt++) v[nt] = (f32x4){0.f,0.f,0.f,0.f};
  const ushort* ug = (const ushort*)un;
  for (int kc=0; kc<4; kc++){
    #pragma unroll
    for (int it=0; it<4; it++){
      int q = tid + it*512;          // < 2048 ushort4
      int y = q >> 4, c4 = q & 15;
      *(ushort4*)&unc[y*UST + c4*4] =
          *(const ushort4*)(ug + (((size_t)b*NY + y)*NX + m)*DIM + kc*64 + c4*4);
    }
    __syncthreads();
    #pragma unroll
    for (int kb=0; kb<2; kb++){
      short8 a2 = *(const short8*)&unc[(w*16 + am)*UST + kb*32 + aq*8];
      int kbg = kc*2 + kb;           // of 8
      short8 bb[4];
      #pragma unroll
      for (int nt=0;nt<4;nt++)
        bb[nt] = *(const short8*)&WvP[(size_t)((kbg*32 + (h*4+nt))*64 + lane)*8];
      #pragma unroll
      for (int nt=0;nt<4;nt++)
        v[nt] = __builtin_amdgcn_mfma_f32_16x16x32_bf16(a2, bb[nt], v[nt], 0,0,0);
    }
    __syncthreads();
  }
  // V frags -> Vt transposed [c][y]
  #pragma unroll
  for (int nt=0;nt<4;nt++){
    int c = nt*16 + am;
    int y0 = w*16 + aq*4;
    ushort4 pk;
    pk.x = (ushort)f2s(v[nt][0]);
    pk.y = (ushort)f2s(v[nt][1]);
    pk.z = (ushort)f2s(v[nt][2]);
    pk.w = (ushort)f2s(v[nt][3]);
    *(ushort4*)&Vt[c*VST + y0] = pk;
  }
  __syncthreads();

  // ---- phase 2: P1 = attnY @ V (rows i = w*16..+15, cols 64 c, K=128)
  f32x4 o[4];
  #pragma unroll
  for (int nt=0;nt<4;nt++) o[nt] = (f32x4){0.f,0.f,0.f,0.f};
  #pragma unroll
  for (int kb=0; kb<4; kb++){
    short8 a2 = *(const short8*)&At[(w*16 + am)*AST + kb*32 + aq*8];
    short8 bb[4];
    #pragma unroll
    for (int nt=0;nt<4;nt++)
      bb[nt] = *(const short8*)&Vt[(nt*16 + am)*VST + kb*32 + aq*8];
    #pragma unroll
    for (int nt=0;nt<4;nt++)
      o[nt] = __builtin_amdgcn_mfma_f32_16x16x32_bf16(a2, bb[nt], o[nt], 0,0,0);
  }
  // write P1 -> phi[bh][i][m][c]
  ushort* pg = (ushort*)phi + (size_t)bh*NY*NX*DH_ + (size_t)m*DH_;
  #pragma unroll
  for (int nt=0;nt<4;nt++)
    #pragma unroll
    for (int reg=0;reg<4;reg++){
      int i = w*16 + aq*4 + reg;
      int c = nt*16 + am;
      pg[(size_t)i*(NX*DH_) + c] = (ushort)f2s(o[nt][reg]);
    }
}

// ---------------------------------------------------------------- MFMA phi2: x-attention + fused GroupNorm
// GN applied IN-REGISTER on the f32 accumulators before rounding (self-consistent).
__global__ void __launch_bounds__(512) k_phi2m(const bf16_t* __restrict__ attn,
    bf16_t* __restrict__ phi){
  int i  = blockIdx.x & (NY-1);
  int bh = blockIdx.x >> 7;
  __shared__ __align__(16) short Ax[128*AST];   // 34.8 KB
  __shared__ __align__(16) short Pt[64*VST];    // 17.4 KB  [c][m]
  int tid = threadIdx.x;
  int lane = tid & 63, w = tid >> 6;            // w in 0..7
  int am = lane & 15, aq = lane >> 4;

  {
    const ushort* ag = (const ushort*)attn + (size_t)bh*16384;
    #pragma unroll
    for (int it=0; it<8; it++){
      int q = tid + it*512;
      int r = q >> 5, j4 = q & 31;
      *(ushort4*)&Ax[r*AST + j4*4] = *(const ushort4*)(ag + r*128 + j4*4);
    }
  }
  ushort* pg = (ushort*)phi + (size_t)(bh*NY + i)*(NX*DH_);
  #pragma unroll
  for (int it=0; it<4; it++){
    int q = tid + it*512;            // < 2048 ushort4
    int mm = q >> 4, c4 = q & 15;
    ushort4 v4 = *(const ushort4*)(pg + mm*DH_ + c4*4);
    Pt[(c4*4+0)*VST + mm] = v4.x;
    Pt[(c4*4+1)*VST + mm] = v4.y;
    Pt[(c4*4+2)*VST + mm] = v4.z;
    Pt[(c4*4+3)*VST + mm] = v4.w;
  }
  __syncthreads();

  f32x4 o[4];
  #pragma unroll
  for (int nt=0;nt<4;nt++) o[nt] = (f32x4){0.f,0.f,0.f,0.f};
  #pragma unroll
  for (int kb=0; kb<4; kb++){
    short8 a2 = *(const short8*)&Ax[(w*16 + am)*AST + kb*32 + aq*8];
    short8 bb[4];
    #pragma unroll
    for (int nt=0;nt<4;nt++)
      bb[nt] = *(const short8*)&Pt[(nt*16 + am)*VST + kb*32 + aq*8];
    #pragma unroll
    for (int nt=0;nt<4;nt++)
      o[nt] = __builtin_amdgcn_mfma_f32_16x16x32_bf16(a2, bb[nt], o[nt], 0,0,0);
  }
  // in-register GroupNorm: row l = w*16 + aq*4 + reg; butterfly over am bits.
  #pragma unroll
  for (int reg=0;reg<4;reg++){
    float s  = o[0][reg]+o[1][reg]+o[2][reg]+o[3][reg];
    float ss = o[0][reg]*o[0][reg]+o[1][reg]*o[1][reg]
             + o[2][reg]*o[2][reg]+o[3][reg]*o[3][reg];
    #pragma unroll
    for (int msk=1; msk<16; msk<<=1){
      s  += __shfl_xor(s,  msk, 64);
      ss += __shfl_xor(ss, msk, 64);
    }
    float mm = s*(1.0f/64.0f);
    float vv = ss*(1.0f/64.0f) - mm*mm;
    float rs = rsqrtf(vv + 1e-6f);
    #pragma unroll
    for (int nt=0;nt<4;nt++)
      o[nt][reg] = (o[nt][reg]-mm)*rs;
  }
  // write normalized P2 in place: phi[bh][i][l][c]
  #pragma unroll
  for (int nt=0;nt<4;nt++)
    #pragma unroll
    for (int reg=0;reg<4;reg++){
      int l = w*16 + aq*4 + reg;
      int c = nt*16 + am;
      pg[(size_t)l*DH_ + c] = (ushort)f2s(o[nt][reg]);
    }
}

// ---------------------------------------------------------------- fused tail:
// stage phi (pre-normalized) -> @Wm (C-in = bm+u residual, loads overlap
// staging) -> LN2 (reg stats) -> MLP (acc init = u2, weights double-buffered
// in registers to hide L2 latency) -> out.
#define GN_ST 520
#define ML_ST 264
__global__ void __launch_bounds__(512, 4) k_tail(const bf16_t* __restrict__ phi,
    const short* __restrict__ WmP, const float* __restrict__ bm,
    const float* __restrict__ u,
    const float* __restrict__ g2, const float* __restrict__ b2,
    const short* __restrict__ Wf1P, const float* __restrict__ bf1,
    const short* __restrict__ Wf2P, const float* __restrict__ bf2,
    float* __restrict__ out){
  __shared__ __align__(16) short SMEM[64*ML_ST*2];   // 67.6 KB: Xg | (Xm , H)
  __shared__ float prow[64][4], prow2[64][4];        // LN2 per-wl partials
  __shared__ float mrow[64], rrow[64];
  short* Xg = SMEM;             // [64][GN_ST]  (66.6 KB <= 67.6)
  short* Xm = SMEM;             // [64][ML_ST]
  short* H  = SMEM + 64*ML_ST;  // [64][ML_ST]
  int tid = threadIdx.x;
  int lane = tid & 63, w = tid >> 6;
  int wh = w >> 2, wl = w & 3;
  int am = lane & 15, aq = lane >> 4;
  size_t p0 = (size_t)blockIdx.x*64;
  int b  = (int)(p0 >> 14);
  int y  = (int)((p0 >> 7) & 127);
  int x0 = (int)(p0 & 127);

  // ---- stage phi (pre-normalized) -> Xg
  #pragma unroll
  for (int it=0; it<16; it++){
    int q = tid + it*512;            // < 8192 ushort4 (64 rows x 512 f)
    int r = q >> 7, f4 = q & 127;
    int h = f4 >> 4, c4 = f4 & 15;
    size_t gi = (((size_t)b*NH + h)*NY + y)*NX + (x0 + r);
    *(ushort4*)&Xg[r*GN_ST + f4*4] =
        *(const ushort4*)((const ushort*)phi + gi*DH_ + c4*4);
  }
  // ---- Wm accumulator init = bm + u residual (loads overlap staging/barrier)
  f32x4 u2r[2][4];
  #pragma unroll
  for (int nt=0;nt<4;nt++){
    int col = wl*64 + nt*16 + am;
    float bmv = bm[col];
    #pragma unroll
    for (int mt=0;mt<2;mt++){
      #pragma unroll
      for (int reg=0;reg<4;reg++){
        size_t p = p0 + wh*32 + mt*16 + aq*4 + reg;
        u2r[mt][nt][reg] = bmv + u[p*DIM + col];
      }
    }
  }
  __syncthreads();

  // ---- Wm GEMM, weights double-buffered in registers
  {
    short8 wnext[4];
    #pragma unroll
    for (int nt=0;nt<4;nt++)
      wnext[nt] = *(const short8*)&WmP[(size_t)(((wl*4+nt))*64 + lane)*8];
    #pragma unroll
    for (int kb=0; kb<16; kb++){
      short8 cw[4];
      #pragma unroll
      for (int nt=0;nt<4;nt++) cw[nt] = wnext[nt];
      if (kb < 15){
        #pragma unroll
        for (int nt=0;nt<4;nt++)
          wnext[nt] = *(const short8*)&WmP[(size_t)(((kb+1)*16 + (wl*4+nt))*64 + lane)*8];
      }
      short8 a[2];
      #pragma unroll
      for (int mt=0;mt<2;mt++)
        a[mt] = *(const short8*)&Xg[(wh*32 + mt*16 + am)*GN_ST + kb*32 + aq*8];
      #pragma unroll
      for (int mt=0;mt<2;mt++)
        #pragma unroll
        for (int nt=0;nt<4;nt++)
          u2r[mt][nt] = __builtin_amdgcn_mfma_f32_16x16x32_bf16(a[mt], cw[nt], u2r[mt][nt], 0,0,0);
    }
  }

  // ---- LN2 stats from regs: butterfly over 16-lane group, combine wl via LDS
  #pragma unroll
  for (int mt=0;mt<2;mt++){
    #pragma unroll
    for (int reg=0;reg<4;reg++){
      float s  = u2r[mt][0][reg]+u2r[mt][1][reg]+u2r[mt][2][reg]+u2r[mt][3][reg];
      float ss = u2r[mt][0][reg]*u2r[mt][0][reg]+u2r[mt][1][reg]*u2r[mt][1][reg]
               + u2r[mt][2][reg]*u2r[mt][2][reg]+u2r[mt][3][reg]*u2r[mt][3][reg];
      #pragma unroll
      for (int msk=1; msk<16; msk<<=1){
        s  += __shfl_xor(s,  msk, 64);
        ss += __shfl_xor(ss, msk, 64);
      }
      if (am == 0){
        int r = wh*32 + mt*16 + aq*4 + reg;
        prow[r][wl] = s;
        prow2[r][wl] = ss;
      }
    }
  }
  __syncthreads();
  if (tid < 64){
    float s  = prow[tid][0]+prow[tid][1]+prow[tid][2]+prow[tid][3];
    float ss = prow2[tid][0]+prow2[tid][1]+prow2[tid][2]+prow2[tid][3];
    float m = s*(1.0f/DIM);
    mrow[tid] = m;
    rrow[tid] = rsqrtf(ss*(1.0f/DIM) - m*m + 1e-5f);
  }
  __syncthreads();
  // ---- normalize -> Xm (reuses Xg space; all waves past the Wm GEMM by now)
  #pragma unroll
  for (int nt=0;nt<4;nt++){
    int col = wl*64 + nt*16 + am;
    float gg = g2[col], bb2 = b2[col];
    #pragma unroll
    for (int mt=0;mt<2;mt++){
      #pragma unroll
      for (int reg=0;reg<4;reg++){
        int r = wh*32 + mt*16 + aq*4 + reg;
        Xm[r*ML_ST + col] = f2s((u2r[mt][nt][reg]-mrow[r])*rrow[r]*gg + bb2);
      }
    }
  }
  __syncthreads();

  // ---- MLP: acc o2 initialized with u2r (fused residual)
  f32x4 o2[2][4];
  #pragma unroll
  for (int mt=0;mt<2;mt++)
    #pragma unroll
    for (int nt=0;nt<4;nt++) o2[mt][nt] = u2r[mt][nt];

  for (int nc=0; nc<4; nc++){
    f32x4 hacc[2][4];
    #pragma unroll
    for (int mt=0;mt<2;mt++)
      #pragma unroll
      for (int nt=0;nt<4;nt++) hacc[mt][nt] = (f32x4){0.f,0.f,0.f,0.f};
    {
      short8 wnext[4];
      #pragma unroll
      for (int nt=0;nt<4;nt++){
        int ntg = nc*16 + wl*4 + nt;
        wnext[nt] = *(const short8*)&Wf1P[(size_t)((ntg)*64 + lane)*8];
      }
      #pragma unroll
      for (int kb=0; kb<8; kb++){
        short8 cw[4];
        #pragma unroll
        for (int nt=0;nt<4;nt++) cw[nt] = wnext[nt];
        if (kb < 7){
          #pragma unroll
          for (int nt=0;nt<4;nt++){
            int ntg = nc*16 + wl*4 + nt;
            wnext[nt] = *(const short8*)&Wf1P[(size_t)(((kb+1)*64 + ntg)*64 + lane)*8];
          }
        }
        short8 a[2];
        #pragma unroll
        for (int mt=0;mt<2;mt++)
          a[mt] = *(const short8*)&Xm[(wh*32 + mt*16 + am)*ML_ST + kb*32 + aq*8];
        #pragma unroll
        for (int mt=0;mt<2;mt++)
          #pragma unroll
          for (int nt=0;nt<4;nt++)
            hacc[mt][nt] = __builtin_amdgcn_mfma_f32_16x16x32_bf16(a[mt], cw[nt], hacc[mt][nt], 0,0,0);
      }
    }
    #pragma unroll
    for (int nt=0;nt<4;nt++){
      int col_l = wl*64 + nt*16 + am;
      float bv = bf1[nc*256 + col_l];
      #pragma unroll
      for (int mt=0;mt<2;mt++){
        #pragma unroll
        for (int reg=0;reg<4;reg++){
          int row = wh*32 + mt*16 + aq*4 + reg;
          H[row*ML_ST + col_l] = f2s(gelu_tanh(hacc[mt][nt][reg] + bv));
        }
      }
    }
    __syncthreads();
    {
      short8 wnext[4];
      #pragma unroll
      for (int nt=0;nt<4;nt++)
        wnext[nt] = *(const short8*)&Wf2P[(size_t)(((nc*8)*16 + (wl*4+nt))*64 + lane)*8];
      #pragma unroll
      for (int kb=0; kb<8; kb++){
        short8 cw[4];
        #pragma unroll
        for (int nt=0;nt<4;nt++) cw[nt] = wnext[nt];
        if (kb < 7){
          int kbg = nc*8 + kb + 1;
          #pragma unroll
          for (int nt=0;nt<4;nt++)
            wnext[nt] = *(const short8*)&Wf2P[(size_t)((kbg*16 + (wl*4+nt))*64 + lane)*8];
        }
        short8 a[2];
        #pragma unroll
        for (int mt=0;mt<2;mt++)
          a[mt] = *(const short8*)&H[(wh*32 + mt*16 + am)*ML_ST + kb*32 + aq*8];
        #pragma unroll
        for (int mt=0;mt<2;mt++)
          #pragma unroll
          for (int nt=0;nt<4;nt++)
            o2[mt][nt] = __builtin_amdgcn_mfma_f32_16x16x32_bf16(a[mt], cw[nt], o2[mt][nt], 0,0,0);
      }
    }
    __syncthreads();
  }

  // ---- epilogue: out = o2 (includes u2 residual) + bf2
  #pragma unroll
  for (int nt=0;nt<4;nt++){
    int col = wl*64 + nt*16 + am;
    float bv = bf2[col];
    #pragma unroll
    for (int mt=0;mt<2;mt++){
      #pragma unroll
      for (int reg=0;reg<4;reg++){
        size_t p = p0 + wh*32 + mt*16 + aq*4 + reg;
        out[p*DIM + col] = o2[mt][nt][reg] + bv;
      }
    }
  }
}

extern "C" void kernel_launch(void* const* d_in, const int* in_sizes, int n_in,
                              void* d_out, int out_size, void* d_ws, size_t ws_size,
                              hipStream_t stream){
  const float* u    = (const float*)d_in[0];
  const float* rcy  = (const float*)d_in[1];
  const float* rsy  = (const float*)d_in[2];
  const float* rcx  = (const float*)d_in[3];
  const float* rsx  = (const float*)d_in[4];
  const float* ln1g = (const float*)d_in[6];
  const float* ln1b = (const float*)d_in[7];
  const float* ln2g = (const float*)d_in[8];
  const float* ln2b = (const float*)d_in[9];
  const float* Wv   = (const float*)d_in[10];
  const float* Wyin = (const float*)d_in[11];
  const float* Wy1  = (const float*)d_in[12];
  const float* by1  = (const float*)d_in[13];
  const float* Wy2  = (const float*)d_in[14];
  const float* by2  = (const float*)d_in[15];
  const float* Wxin = (const float*)d_in[16];
  const float* Wx1  = (const float*)d_in[17];
  const float* bx1  = (const float*)d_in[18];
  const float* Wx2  = (const float*)d_in[19];
  const float* bx2  = (const float*)d_in[20];
  const float* Wqkx = (const float*)d_in[21];
  const float* Wqky = (const float*)d_in[22];
  const float* Wm   = (const float*)d_in[23];
  const float* bm   = (const float*)d_in[24];
  const float* Wf1  = (const float*)d_in[25];
  const float* bf1  = (const float*)d_in[26];
  const float* Wf2  = (const float*)d_in[27];
  const float* bf2  = (const float*)d_in[28];

  char* w = (char*)d_ws;
  auto alloc = [&](size_t n) -> void* {
    void* p = (void*)w;
    w += (n + 255) & ~(size_t)255;
    return p;
  };
  bf16_t* UN   = (bf16_t*)alloc((size_t)NPOS*DIM*2);               // 32 MiB
  bf16_t* PHI  = (bf16_t*)alloc((size_t)NB*NH*NY*NX*DH_*2);        // 64 MiB
  float* POOLY = (float*)alloc((size_t)NB*NY*DIM*4);
  float* POOLX = (float*)alloc((size_t)NB*NX*DIM*4);
  float* TY    = (float*)alloc((size_t)512*256*4);
  float* TX    = (float*)alloc((size_t)512*256*4);
  float* HY    = (float*)alloc((size_t)512*1024*4);
  float* HX    = (float*)alloc((size_t)512*1024*4);
  float* UY    = (float*)alloc((size_t)512*256*4);
  float* UX    = (float*)alloc((size_t)512*256*4);
  float* QKY   = (float*)alloc((size_t)512*1024*4);
  float* QKX   = (float*)alloc((size_t)512*1024*4);
  float* QRY   = (float*)alloc((size_t)NB*NH*128*64*4);
  float* KRY   = (float*)alloc((size_t)NB*NH*128*64*4);
  float* QRX   = (float*)alloc((size_t)NB*NH*128*64*4);
  float* KRX   = (float*)alloc((size_t)NB*NH*128*64*4);
  bf16_t* ATTNY = (bf16_t*)alloc((size_t)NB*NH*128*128*2);
  bf16_t* ATTNX = (bf16_t*)alloc((size_t)NB*NH*128*128*2);
  short* WF1P  = (short*)alloc((size_t)256*1024*2);
  short* WF2P  = (short*)alloc((size_t)1024*256*2);
  short* WMP   = (short*)alloc((size_t)512*256*2);
  short* WVP   = (short*)alloc((size_t)256*512*2);
  short* WYINP = (short*)alloc((size_t)256*256*2);
  short* WY1P  = (short*)alloc((size_t)256*1024*2);
  short* WY2P  = (short*)alloc((size_t)1024*256*2);
  short* WQKYP = (short*)alloc((size_t)256*1024*2);
  short* WXINP = (short*)alloc((size_t)256*256*2);
  short* WX1P  = (short*)alloc((size_t)256*1024*2);
  short* WX2P  = (short*)alloc((size_t)1024*256*2);
  short* WQKXP = (short*)alloc((size_t)256*1024*2);
  float* U2 = (float*)d_out;
  (void)in_sizes; (void)n_in; (void)out_size; (void)ws_size;

  // ---- all weight packs in one launch
  PackArgs pa;
  const float* srcs[12] = {Wf1,Wf2,Wm,Wv,Wyin,Wy1,Wy2,Wqky,Wxin,Wx1,Wx2,Wqkx};
  short* dsts[12] = {WF1P,WF2P,WMP,WVP,WYINP,WY1P,WY2P,WQKYP,WXINP,WX1P,WX2P,WQKXP};
  int Ks[12] = {256,1024,512,256,256,256,1024,256,256,256,1024,256};
  int Ns[12] = {1024,256,256,512,256,1024,256,1024,256,1024,256,1024};
  int boffs[12] = {0,128,256,320,384,416,544,672,800,832,960,1088};
  for (int i=0;i<12;i++){
    pa.src[i]=srcs[i]; pa.dst[i]=dsts[i]; pa.K[i]=Ks[i]; pa.N[i]=Ns[i]; pa.boff[i]=boffs[i];
  }
  k_pack_all<<<1216, 256, 0, stream>>>(pa);

  k_ln1<<<NPOS/4, 256, 0, stream>>>(u, ln1g, ln1b, UN);
  k_pool_y<<<NB*NY, 1024, 0, stream>>>(UN, POOLY);
  k_pool_x<<<NB*NX, 1024, 0, stream>>>(UN, POOLX);

  // x/y chains fused via grid.z: pool -> Win -> gelu-MLP -> QK
  k_gemm2<<<dim3(8,1,2), 256, 0, stream>>>(POOLY, POOLX, WYINP, WXINP,
      (const float*)nullptr, (const float*)nullptr, TY, TX, 256, 256, 0);
  k_gemm2<<<dim3(8,4,2), 256, 0, stream>>>(TY, TX, WY1P, WX1P, by1, bx1, HY, HX, 1024, 256, 1);
  k_gemm2<<<dim3(8,1,2), 256, 0, stream>>>(HY, HX, WY2P, WX2P, by2, bx2, UY, UX, 256, 1024, 0);
  k_gemm2<<<dim3(8,4,2), 256, 0, stream>>>(UY, UX, WQKYP, WQKXP,
      (const float*)nullptr, (const float*)nullptr, QKY, QKX, 1024, 256, 0);

  k_rope2<<<dim3((NB*128*1024)/256, 2), 256, 0, stream>>>(QKY, QKX,
      rcy, rsy, rcx, rsx, QRY, KRY, QRX, KRX);
  k_attn2<<<dim3(NB*NH*128, 2), 128, 0, stream>>>(QRY, KRY, ATTNY, QRX, KRX, ATTNX);
  k_phi1m<<<NB*NH*NX, 512, 0, stream>>>(UN, WVP, ATTNY, PHI);
  k_phi2m<<<NB*NH*NY, 512, 0, stream>>>(ATTNX, PHI);
  k_tail<<<NPOS/64, 512, 0, stream>>>(PHI, WMP, bm, u, ln2g, ln2b,
      WF1P, bf1, WF2P, bf2, U2);
}

// Round 10
// 594.829 us; speedup vs baseline: 1.0819x; 1.0819x over previous
//
#include <hip/hip_runtime.h>
#include <hip/hip_bf16.h>
#include <math.h>

// Problem constants (B=4, 128x128 grid, DIM=256, 8 heads x 64)
#define NB 4
#define NY 128
#define NX 128
#define DIM 256
#define NH 8
#define DH_ 64
#define HDIM 512   // NH*DH
#define HID 1024
#define NPOS (NB*NY*NX)   // 65536

typedef __hip_bfloat16 bf16_t;
typedef __attribute__((ext_vector_type(8))) short short8;   // 8 bf16 = 1 MFMA A/B frag
typedef __attribute__((ext_vector_type(4))) float f32x4;    // MFMA C/D frag

__device__ __forceinline__ float b2f(bf16_t x){ return __bfloat162float(x); }
__device__ __forceinline__ bf16_t f2b(float x){ return __float2bfloat16(x); }
__device__ __forceinline__ short f2s(float x){ bf16_t h = __float2bfloat16(x); return *reinterpret_cast<short*>(&h); }
__device__ __forceinline__ float s2f(short x){ bf16_t h = *reinterpret_cast<bf16_t*>(&x); return __bfloat162float(h); }

// MFMA fragment layout (gfx950, verified):
//  A[m][k]: m = lane&15, k = (lane>>4)*8 + j
//  B[k][n]: n = lane&15, k = (lane>>4)*8 + j
//  D[row][col]: col = lane&15, row = (lane>>4)*4 + reg

// gelu tanh-approx: 0.5x(1+tanh(t)) == x*sigmoid(2t); __expf maps to v_exp_f32.
__device__ __forceinline__ float gelu_tanh(float x){
  float z = 1.5957691216057308f*(x + 0.044715f*x*x*x);
  return x / (1.0f + __expf(-z));
}

// ---------------------------------------------------------------- weight pack, ALL weights in one launch
struct PackArgs {
  const float* src[12];
  short* dst[12];
  int K[12];
  int N[12];
  int boff[12];    // starting block of each weight
};
__global__ void __launch_bounds__(256) k_pack_all(PackArgs pa){
  int idx = 0;
  #pragma unroll
  for (int j=1;j<12;j++) if ((int)blockIdx.x >= pa.boff[j]) idx = j;
  int tid = ((int)blockIdx.x - pa.boff[idx])*256 + threadIdx.x;   // < K*N/8
  const float* W = pa.src[idx];
  short* out = pa.dst[idx];
  int N = pa.N[idx];
  int lane = tid & 63;
  int rem = tid >> 6;
  int ntiles = N >> 4;
  int nt = rem % ntiles, kb = rem / ntiles;
  int n = nt*16 + (lane & 15);
  int k0 = kb*32 + (lane>>4)*8;
  short8 v;
  #pragma unroll
  for (int j=0;j<8;j++) v[j] = f2s(W[(size_t)(k0+j)*N + n]);
  *(short8*)&out[(size_t)tid*8] = v;
}

// ---------------------------------------------------------------- LN1 (f32 in -> bf16 un)
__global__ void __launch_bounds__(256) k_ln1(const float* __restrict__ u,
    const float* __restrict__ g, const float* __restrict__ b,
    bf16_t* __restrict__ un){
  int wave = threadIdx.x >> 6, lane = threadIdx.x & 63;
  size_t row = (size_t)blockIdx.x*4 + wave;
  const float* x = u + row*DIM;
  float v[4]; float s=0.f, ss=0.f;
  #pragma unroll
  for (int j=0;j<4;j++){ float t = x[lane + j*64]; v[j]=t; s+=t; ss+=t*t; }
  #pragma unroll
  for (int off=32;off>0;off>>=1){ s += __shfl_down(s,off,64); ss += __shfl_down(ss,off,64); }
  s = __shfl(s,0,64); ss = __shfl(ss,0,64);
  float m = s*(1.0f/DIM);
  float var = ss*(1.0f/DIM) - m*m;
  float r = rsqrtf(var + 1e-5f);
  bf16_t* o = un + row*DIM;
  #pragma unroll
  for (int j=0;j<4;j++){
    int f = lane + j*64;
    o[f] = f2b((v[j]-m)*r*g[f] + b[f]);
  }
}

// ---------------------------------------------------------------- pooling (bf16 un -> f32)
// 1024 threads: 4-way split of the 128-long reduction (serial chain 128->32)
__global__ void __launch_bounds__(1024) k_pool_y(const bf16_t* __restrict__ un, float* __restrict__ pooly){
  int by = blockIdx.x;                       // b*NY + y
  int d = threadIdx.x & 255, xq = threadIdx.x >> 8;
  __shared__ float part[4][256];
  size_t base = (size_t)by*NX*DIM + d;
  float s = 0.f;
  int x0 = xq*32;
  for (int x=x0; x<x0+32; x++) s += b2f(un[base + (size_t)x*DIM]);
  part[xq][d] = s;
  __syncthreads();
  if (threadIdx.x < 256)
    pooly[(size_t)by*DIM + d] = (part[0][d]+part[1][d]+part[2][d]+part[3][d])*(1.0f/NX);
}
__global__ void __launch_bounds__(1024) k_pool_x(const bf16_t* __restrict__ un, float* __restrict__ poolx){
  int bb = blockIdx.x / NX, x = blockIdx.x % NX;
  int d = threadIdx.x & 255, yq = threadIdx.x >> 8;
  __shared__ float part[4][256];
  size_t base = ((size_t)bb*NY*NX + x)*DIM + d;
  float s = 0.f;
  int y0 = yq*32;
  for (int y=y0; y<y0+32; y++) s += b2f(un[base + (size_t)y*NX*DIM]);
  part[yq][d] = s;
  __syncthreads();
  if (threadIdx.x < 256)
    poolx[(size_t)blockIdx.x*DIM + d] = (part[0][d]+part[1][d]+part[2][d]+part[3][d])*(1.0f/NY);
}

// ---------------------------------------------------------------- MFMA GEMM, x/y chains fused via blockIdx.z
// C[M x N] = op(A[M x K] @ W + bias); grid = (M/64, N/256, 2), block 256.
#define GS_STRIDE 72
__global__ void __launch_bounds__(256) k_gemm2(const float* __restrict__ A0,
    const float* __restrict__ A1,
    const short* __restrict__ W0, const short* __restrict__ W1,
    const float* __restrict__ b0, const float* __restrict__ b1,
    float* __restrict__ C0, float* __restrict__ C1, int N, int K, int dogelu){
  const float* A  = blockIdx.z ? A1 : A0;
  const short* WP = blockIdx.z ? W1 : W0;
  const float* bias = blockIdx.z ? b1 : b0;
  float* C = blockIdx.z ? C1 : C0;
  __shared__ __align__(16) short As[64*GS_STRIDE];   // 9.2 KB
  int tid = threadIdx.x;
  int lane = tid & 63, w = tid >> 6;
  int am = lane & 15, aq = lane >> 4;
  int m0 = blockIdx.x*64;
  int nt0 = blockIdx.y*16;
  int ntiles = N >> 4;
  f32x4 o[4][4];
  #pragma unroll
  for (int mt=0;mt<4;mt++)
    #pragma unroll
    for (int nt=0;nt<4;nt++) o[mt][nt] = (f32x4){0.f,0.f,0.f,0.f};

  for (int kc=0; kc<K; kc+=64){
    #pragma unroll
    for (int it=0; it<4; it++){
      int q = tid + it*256;
      int r = q >> 4, c4 = q & 15;
      float4 v = *(const float4*)&A[(size_t)(m0+r)*K + kc + c4*4];
      ushort4 p;
      p.x = (ushort)f2s(v.x); p.y = (ushort)f2s(v.y);
      p.z = (ushort)f2s(v.z); p.w = (ushort)f2s(v.w);
      *(ushort4*)&As[r*GS_STRIDE + c4*4] = p;
    }
    __syncthreads();
    #pragma unroll
    for (int kb=0; kb<2; kb++){
      short8 a[4], bfr[4];
      #pragma unroll
      for (int mt=0;mt<4;mt++)
        a[mt] = *(const short8*)&As[(mt*16+am)*GS_STRIDE + kb*32 + aq*8];
      int kbg = (kc>>5) + kb;
      #pragma unroll
      for (int nt=0;nt<4;nt++){
        int ntg = nt0 + w*4 + nt;
        bfr[nt] = *(const short8*)&WP[(size_t)((kbg*ntiles + ntg)*64 + lane)*8];
      }
      #pragma unroll
      for (int mt=0;mt<4;mt++)
        #pragma unroll
        for (int nt=0;nt<4;nt++)
          o[mt][nt] = __builtin_amdgcn_mfma_f32_16x16x32_bf16(a[mt], bfr[nt], o[mt][nt], 0,0,0);
    }
    __syncthreads();
  }

  #pragma unroll
  for (int nt=0;nt<4;nt++){
    int col = (nt0 + w*4 + nt)*16 + am;
    float bv = bias ? bias[col] : 0.f;
    #pragma unroll
    for (int mt=0;mt<4;mt++){
      #pragma unroll
      for (int reg=0;reg<4;reg++){
        int row = m0 + mt*16 + aq*4 + reg;
        float val = o[mt][nt][reg] + bv;
        if (dogelu) val = gelu_tanh(val);
        C[(size_t)row*N + col] = val;
      }
    }
  }
}

// ---------------------------------------------------------------- RoPE split, y+x fused via blockIdx.y
__global__ void __launch_bounds__(256) k_rope2(const float* __restrict__ qky,
    const float* __restrict__ qkx,
    const float* __restrict__ csy, const float* __restrict__ sny,
    const float* __restrict__ csx, const float* __restrict__ snx,
    float* __restrict__ qy, float* __restrict__ ky,
    float* __restrict__ qx, float* __restrict__ kx){
  const float* qk = blockIdx.y ? qkx : qky;
  const float* cs = blockIdx.y ? csx : csy;
  const float* sn = blockIdx.y ? snx : sny;
  float* q = blockIdx.y ? qx : qy;
  float* k = blockIdx.y ? kx : ky;
  int idx = blockIdx.x*256 + threadIdx.x;
  int c = idx & 63;
  int h = (idx>>6) & 7;
  int p = (idx>>9) & 1;
  int n = (idx>>10) & 127;
  int bb = idx>>17;
  float t = qk[idx];
  float t2 = qk[(c<32) ? idx+32 : idx-32];
  if (c<32) t2 = -t2;
  float val = t*cs[n*64+c] + t2*sn[n*64+c];
  float* dst = p ? k : q;
  dst[(((size_t)bb*NH + h)*128 + n)*64 + c] = val;
}

// ---------------------------------------------------------------- attention matrix, y+x fused via blockIdx.y
__global__ void __launch_bounds__(128) k_attn2(const float* __restrict__ qy,
    const float* __restrict__ ky, bf16_t* __restrict__ ay,
    const float* __restrict__ qx, const float* __restrict__ kx,
    bf16_t* __restrict__ ax){
  const float* q = blockIdx.y ? qx : qy;
  const float* k = blockIdx.y ? kx : ky;
  bf16_t* attn = blockIdx.y ? ax : ay;
  int i = blockIdx.x & 127;
  int bh = blockIdx.x >> 7;
  __shared__ float qs[64];
  __shared__ float red[4];
  int tid = threadIdx.x;
  int wv = tid >> 6, lane = tid & 63;
  const float* qrow = q + ((size_t)bh*128 + i)*64;
  if (tid < 64) qs[tid] = qrow[tid];
  __syncthreads();
  const float* krow = k + ((size_t)bh*128 + tid)*64;
  float dot = 0.f;
  for (int c=0;c<64;c++) dot += qs[c]*krow[c];
  dot *= (1.0f/64.0f);
  float mx = dot;
  #pragma unroll
  for (int off=32;off>0;off>>=1) mx = fmaxf(mx, __shfl_xor(mx, off, 64));
  if (lane == 0) red[wv] = mx;
  __syncthreads();
  mx = fmaxf(red[0], red[1]);
  float e = __expf(dot - mx);
  float s = e;
  #pragma unroll
  for (int off=32;off>0;off>>=1) s += __shfl_xor(s, off, 64);
  if (lane == 0) red[2+wv] = s;
  __syncthreads();
  s = red[2] + red[3];
  attn[(size_t)blockIdx.x*128 + tid] = f2b(e/s);
}

// ---------------------------------------------------------------- MFMA phi1: V-proj + y-attention
// 512 threads = 8 waves, each owning 16 rows.
#define AST 136   // 128 + 8 shorts
#define UST 72    // 64 + 8 shorts
#define VST 136
__global__ void __launch_bounds__(512) k_phi1m(const bf16_t* __restrict__ un,
    const short* __restrict__ WvP, const bf16_t* __restrict__ attn,
    bf16_t* __restrict__ phi){
  int m  = blockIdx.x & (NX-1);
  int bh = blockIdx.x >> 7;
  int b  = bh >> 3, h = bh & 7;
  __shared__ __align__(16) short At[128*AST];   // 34.8 KB
  __shared__ __align__(16) short unc[128*UST];  // 18.4 KB
  __shared__ __align__(16) short Vt[64*VST];    // 17.4 KB  [c][y]
  int tid = threadIdx.x;
  int lane = tid & 63, w = tid >> 6;            // w in 0..7
  int am = lane & 15, aq = lane >> 4;

  // stage attn slice (bh): 128x128 bf16 -> At (read only in phase 2)
  {
    const ushort* ag = (const ushort*)attn + (size_t)bh*16384;
    #pragma unroll
    for (int it=0; it<8; it++){
      int q = tid + it*512;          // < 4096 ushort4
      int i = q >> 5, j4 = q & 31;
      *(ushort4*)&At[i*AST + j4*4] = *(const ushort4*)(ag + i*128 + j4*4);
    }
  }

  // ---- phase 1: V-projection (wave w owns y rows w*16..+15, all 64 c)
  f32x4 v[4];
  #pragma unroll
  for (int nt=0;nt<4;nt++) v[nt] = (f32x4){0.f,0.f,0.f,0.f};
  const ushort* ug = (const ushort*)un;
  for (int kc=0; kc<4; kc++){
    #pragma unroll
    for (int it=0; it<4; it++){
      int q = tid + it*512;          // < 2048 ushort4
      int y = q >> 4, c4 = q & 15;
      *(ushort4*)&unc[y*UST + c4*4] =
          *(const ushort4*)(ug + (((size_t)b*NY + y)*NX + m)*DIM + kc*64 + c4*4);
    }
    __syncthreads();
    #pragma unroll
    for (int kb=0; kb<2; kb++){
      short8 a2 = *(const short8*)&unc[(w*16 + am)*UST + kb*32 + aq*8];
      int kbg = kc*2 + kb;           // of 8
      short8 bb[4];
      #pragma unroll
      for (int nt=0;nt<4;nt++)
        bb[nt] = *(const short8*)&WvP[(size_t)((kbg*32 + (h*4+nt))*64 + lane)*8];
      #pragma unroll
      for (int nt=0;nt<4;nt++)
        v[nt] = __builtin_amdgcn_mfma_f32_16x16x32_bf16(a2, bb[nt], v[nt], 0,0,0);
    }
    __syncthreads();
  }
  // V frags -> Vt transposed [c][y]
  #pragma unroll
  for (int nt=0;nt<4;nt++){
    int c = nt*16 + am;
    int y0 = w*16 + aq*4;
    ushort4 pk;
    pk.x = (ushort)f2s(v[nt][0]);
    pk.y = (ushort)f2s(v[nt][1]);
    pk.z = (ushort)f2s(v[nt][2]);
    pk.w = (ushort)f2s(v[nt][3]);
    *(ushort4*)&Vt[c*VST + y0] = pk;
  }
  __syncthreads();

  // ---- phase 2: P1 = attnY @ V (rows i = w*16..+15, cols 64 c, K=128)
  f32x4 o[4];
  #pragma unroll
  for (int nt=0;nt<4;nt++) o[nt] = (f32x4){0.f,0.f,0.f,0.f};
  #pragma unroll
  for (int kb=0; kb<4; kb++){
    short8 a2 = *(const short8*)&At[(w*16 + am)*AST + kb*32 + aq*8];
    short8 bb[4];
    #pragma unroll
    for (int nt=0;nt<4;nt++)
      bb[nt] = *(const short8*)&Vt[(nt*16 + am)*VST + kb*32 + aq*8];
    #pragma unroll
    for (int nt=0;nt<4;nt++)
      o[nt] = __builtin_amdgcn_mfma_f32_16x16x32_bf16(a2, bb[nt], o[nt], 0,0,0);
  }
  // write P1 -> phi[bh][i][m][c]
  ushort* pg = (ushort*)phi + (size_t)bh*NY*NX*DH_ + (size_t)m*DH_;
  #pragma unroll
  for (int nt=0;nt<4;nt++)
    #pragma unroll
    for (int reg=0;reg<4;reg++){
      int i = w*16 + aq*4 + reg;
      int c = nt*16 + am;
      pg[(size_t)i*(NX*DH_) + c] = (ushort)f2s(o[nt][reg]);
    }
}

// ---------------------------------------------------------------- MFMA phi2: x-attention + fused GroupNorm
// GN applied IN-REGISTER on the f32 accumulators before rounding (self-consistent).
__global__ void __launch_bounds__(512) k_phi2m(const bf16_t* __restrict__ attn,
    bf16_t* __restrict__ phi){
  int i  = blockIdx.x & (NY-1);
  int bh = blockIdx.x >> 7;
  __shared__ __align__(16) short Ax[128*AST];   // 34.8 KB
  __shared__ __align__(16) short Pt[64*VST];    // 17.4 KB  [c][m]
  int tid = threadIdx.x;
  int lane = tid & 63, w = tid >> 6;            // w in 0..7
  int am = lane & 15, aq = lane >> 4;

  {
    const ushort* ag = (const ushort*)attn + (size_t)bh*16384;
    #pragma unroll
    for (int it=0; it<8; it++){
      int q = tid + it*512;
      int r = q >> 5, j4 = q & 31;
      *(ushort4*)&Ax[r*AST + j4*4] = *(const ushort4*)(ag + r*128 + j4*4);
    }
  }
  ushort* pg = (ushort*)phi + (size_t)(bh*NY + i)*(NX*DH_);
  #pragma unroll
  for (int it=0; it<4; it++){
    int q = tid + it*512;            // < 2048 ushort4
    int mm = q >> 4, c4 = q & 15;
    ushort4 v4 = *(const ushort4*)(pg + mm*DH_ + c4*4);
    Pt[(c4*4+0)*VST + mm] = v4.x;
    Pt[(c4*4+1)*VST + mm] = v4.y;
    Pt[(c4*4+2)*VST + mm] = v4.z;
    Pt[(c4*4+3)*VST + mm] = v4.w;
  }
  __syncthreads();

  f32x4 o[4];
  #pragma unroll
  for (int nt=0;nt<4;nt++) o[nt] = (f32x4){0.f,0.f,0.f,0.f};
  #pragma unroll
  for (int kb=0; kb<4; kb++){
    short8 a2 = *(const short8*)&Ax[(w*16 + am)*AST + kb*32 + aq*8];
    short8 bb[4];
    #pragma unroll
    for (int nt=0;nt<4;nt++)
      bb[nt] = *(const short8*)&Pt[(nt*16 + am)*VST + kb*32 + aq*8];
    #pragma unroll
    for (int nt=0;nt<4;nt++)
      o[nt] = __builtin_amdgcn_mfma_f32_16x16x32_bf16(a2, bb[nt], o[nt], 0,0,0);
  }
  // in-register GroupNorm: row l = w*16 + aq*4 + reg; butterfly over am bits.
  #pragma unroll
  for (int reg=0;reg<4;reg++){
    float s  = o[0][reg]+o[1][reg]+o[2][reg]+o[3][reg];
    float ss = o[0][reg]*o[0][reg]+o[1][reg]*o[1][reg]
             + o[2][reg]*o[2][reg]+o[3][reg]*o[3][reg];
    #pragma unroll
    for (int msk=1; msk<16; msk<<=1){
      s  += __shfl_xor(s,  msk, 64);
      ss += __shfl_xor(ss, msk, 64);
    }
    float mm = s*(1.0f/64.0f);
    float vv = ss*(1.0f/64.0f) - mm*mm;
    float rs = rsqrtf(vv + 1e-6f);
    #pragma unroll
    for (int nt=0;nt<4;nt++)
      o[nt][reg] = (o[nt][reg]-mm)*rs;
  }
  // write normalized P2 in place: phi[bh][i][l][c]
  #pragma unroll
  for (int nt=0;nt<4;nt++)
    #pragma unroll
    for (int reg=0;reg<4;reg++){
      int l = w*16 + aq*4 + reg;
      int c = nt*16 + am;
      pg[(size_t)l*DH_ + c] = (ushort)f2s(o[nt][reg]);
    }
}

// ---------------------------------------------------------------- fused tail (r8 verbatim — measured 247 us, no spill):
// stage phi (pre-normalized) -> @Wm+bm+u (u2 in REGS) -> LN2 (reg stats) ->
// MLP (acc init = u2 fused residual) -> out. 512 threads = 8 waves.
#define GN_ST 520
#define ML_ST 264
__global__ void __launch_bounds__(512, 4) k_tail(const bf16_t* __restrict__ phi,
    const short* __restrict__ WmP, const float* __restrict__ bm,
    const float* __restrict__ u,
    const float* __restrict__ g2, const float* __restrict__ b2,
    const short* __restrict__ Wf1P, const float* __restrict__ bf1,
    const short* __restrict__ Wf2P, const float* __restrict__ bf2,
    float* __restrict__ out){
  __shared__ __align__(16) short SMEM[64*ML_ST*2];   // 67.6 KB: Xg | (Xm , H)
  __shared__ float prow[64][4], prow2[64][4];        // LN2 per-wl partials
  __shared__ float mrow[64], rrow[64];
  short* Xg = SMEM;             // [64][GN_ST]  (66.6 KB <= 67.6)
  short* Xm = SMEM;             // [64][ML_ST]
  short* H  = SMEM + 64*ML_ST;  // [64][ML_ST]
  int tid = threadIdx.x;
  int lane = tid & 63, w = tid >> 6;
  int wh = w >> 2, wl = w & 3;
  int am = lane & 15, aq = lane >> 4;
  size_t p0 = (size_t)blockIdx.x*64;
  int b  = (int)(p0 >> 14);
  int y  = (int)((p0 >> 7) & 127);
  int x0 = (int)(p0 & 127);

  // ---- stage phi (pre-normalized) -> Xg
  #pragma unroll
  for (int it=0; it<16; it++){
    int q = tid + it*512;            // < 8192 ushort4 (64 rows x 512 f)
    int r = q >> 7, f4 = q & 127;
    int h = f4 >> 4, c4 = f4 & 15;
    size_t gi = (((size_t)b*NH + h)*NY + y)*NX + (x0 + r);
    *(ushort4*)&Xg[r*GN_ST + f4*4] =
        *(const ushort4*)((const ushort*)phi + gi*DH_ + c4*4);
  }
  __syncthreads();

  // ---- Wm GEMM -> u2 regs (+bm +u residual)
  f32x4 u2r[2][4];
  #pragma unroll
  for (int mt=0;mt<2;mt++)
    #pragma unroll
    for (int nt=0;nt<4;nt++) u2r[mt][nt] = (f32x4){0.f,0.f,0.f,0.f};
  for (int kb=0; kb<16; kb++){
    short8 a[2], bfr[4];
    #pragma unroll
    for (int mt=0;mt<2;mt++)
      a[mt] = *(const short8*)&Xg[(wh*32 + mt*16 + am)*GN_ST + kb*32 + aq*8];
    #pragma unroll
    for (int nt=0;nt<4;nt++)
      bfr[nt] = *(const short8*)&WmP[(size_t)((kb*16 + (wl*4+nt))*64 + lane)*8];
    #pragma unroll
    for (int mt=0;mt<2;mt++)
      #pragma unroll
      for (int nt=0;nt<4;nt++)
        u2r[mt][nt] = __builtin_amdgcn_mfma_f32_16x16x32_bf16(a[mt], bfr[nt], u2r[mt][nt], 0,0,0);
  }
  #pragma unroll
  for (int nt=0;nt<4;nt++){
    int col = wl*64 + nt*16 + am;
    float bmv = bm[col];
    #pragma unroll
    for (int mt=0;mt<2;mt++){
      #pragma unroll
      for (int reg=0;reg<4;reg++){
        size_t p = p0 + wh*32 + mt*16 + aq*4 + reg;
        u2r[mt][nt][reg] += bmv + u[p*DIM + col];
      }
    }
  }

  // ---- LN2 stats from regs: butterfly over 16-lane group, combine wl via LDS
  #pragma unroll
  for (int mt=0;mt<2;mt++){
    #pragma unroll
    for (int reg=0;reg<4;reg++){
      float s  = u2r[mt][0][reg]+u2r[mt][1][reg]+u2r[mt][2][reg]+u2r[mt][3][reg];
      float ss = u2r[mt][0][reg]*u2r[mt][0][reg]+u2r[mt][1][reg]*u2r[mt][1][reg]
               + u2r[mt][2][reg]*u2r[mt][2][reg]+u2r[mt][3][reg]*u2r[mt][3][reg];
      #pragma unroll
      for (int msk=1; msk<16; msk<<=1){
        s  += __shfl_xor(s,  msk, 64);
        ss += __shfl_xor(ss, msk, 64);
      }
      if (am == 0){
        int r = wh*32 + mt*16 + aq*4 + reg;
        prow[r][wl] = s;
        prow2[r][wl] = ss;
      }
    }
  }
  __syncthreads();
  if (tid < 64){
    float s  = prow[tid][0]+prow[tid][1]+prow[tid][2]+prow[tid][3];
    float ss = prow2[tid][0]+prow2[tid][1]+prow2[tid][2]+prow2[tid][3];
    float m = s*(1.0f/DIM);
    mrow[tid] = m;
    rrow[tid] = rsqrtf(ss*(1.0f/DIM) - m*m + 1e-5f);
  }
  __syncthreads();
  // ---- normalize -> Xm (reuses Xg space; all waves past the Wm GEMM by now)
  #pragma unroll
  for (int nt=0;nt<4;nt++){
    int col = wl*64 + nt*16 + am;
    float gg = g2[col], bb2 = b2[col];
    #pragma unroll
    for (int mt=0;mt<2;mt++){
      #pragma unroll
      for (int reg=0;reg<4;reg++){
        int r = wh*32 + mt*16 + aq*4 + reg;
        Xm[r*ML_ST + col] = f2s((u2r[mt][nt][reg]-mrow[r])*rrow[r]*gg + bb2);
      }
    }
  }
  __syncthreads();

  // ---- MLP: acc o2 initialized with u2r (fused residual, frees u2r regs)
  f32x4 o2[2][4];
  #pragma unroll
  for (int mt=0;mt<2;mt++)
    #pragma unroll
    for (int nt=0;nt<4;nt++) o2[mt][nt] = u2r[mt][nt];

  for (int nc=0; nc<4; nc++){
    f32x4 hacc[2][4];
    #pragma unroll
    for (int mt=0;mt<2;mt++)
      #pragma unroll
      for (int nt=0;nt<4;nt++) hacc[mt][nt] = (f32x4){0.f,0.f,0.f,0.f};
    for (int kb=0; kb<8; kb++){
      short8 a[2], bfr[4];
      #pragma unroll
      for (int mt=0;mt<2;mt++)
        a[mt] = *(const short8*)&Xm[(wh*32 + mt*16 + am)*ML_ST + kb*32 + aq*8];
      #pragma unroll
      for (int nt=0;nt<4;nt++){
        int ntg = nc*16 + wl*4 + nt;
        bfr[nt] = *(const short8*)&Wf1P[(size_t)((kb*64 + ntg)*64 + lane)*8];
      }
      #pragma unroll
      for (int mt=0;mt<2;mt++)
        #pragma unroll
        for (int nt=0;nt<4;nt++)
          hacc[mt][nt] = __builtin_amdgcn_mfma_f32_16x16x32_bf16(a[mt], bfr[nt], hacc[mt][nt], 0,0,0);
    }
    #pragma unroll
    for (int nt=0;nt<4;nt++){
      int col_l = wl*64 + nt*16 + am;
      float bv = bf1[nc*256 + col_l];
      #pragma unroll
      for (int mt=0;mt<2;mt++){
        #pragma unroll
        for (int reg=0;reg<4;reg++){
          int row = wh*32 + mt*16 + aq*4 + reg;
          H[row*ML_ST + col_l] = f2s(gelu_tanh(hacc[mt][nt][reg] + bv));
        }
      }
    }
    __syncthreads();
    for (int kb=0; kb<8; kb++){
      short8 a[2], bfr[4];
      #pragma unroll
      for (int mt=0;mt<2;mt++)
        a[mt] = *(const short8*)&H[(wh*32 + mt*16 + am)*ML_ST + kb*32 + aq*8];
      int kbg = nc*8 + kb;
      #pragma unroll
      for (int nt=0;nt<4;nt++)
        bfr[nt] = *(const short8*)&Wf2P[(size_t)((kbg*16 + (wl*4+nt))*64 + lane)*8];
      #pragma unroll
      for (int mt=0;mt<2;mt++)
        #pragma unroll
        for (int nt=0;nt<4;nt++)
          o2[mt][nt] = __builtin_amdgcn_mfma_f32_16x16x32_bf16(a[mt], bfr[nt], o2[mt][nt], 0,0,0);
    }
    __syncthreads();
  }

  // ---- epilogue: out = o2 (includes u2 residual) + bf2
  #pragma unroll
  for (int nt=0;nt<4;nt++){
    int col = wl*64 + nt*16 + am;
    float bv = bf2[col];
    #pragma unroll
    for (int mt=0;mt<2;mt++){
      #pragma unroll
      for (int reg=0;reg<4;reg++){
        size_t p = p0 + wh*32 + mt*16 + aq*4 + reg;
        out[p*DIM + col] = o2[mt][nt][reg] + bv;
      }
    }
  }
}

extern "C" void kernel_launch(void* const* d_in, const int* in_sizes, int n_in,
                              void* d_out, int out_size, void* d_ws, size_t ws_size,
                              hipStream_t stream){
  const float* u    = (const float*)d_in[0];
  const float* rcy  = (const float*)d_in[1];
  const float* rsy  = (const float*)d_in[2];
  const float* rcx  = (const float*)d_in[3];
  const float* rsx  = (const float*)d_in[4];
  const float* ln1g = (const float*)d_in[6];
  const float* ln1b = (const float*)d_in[7];
  const float* ln2g = (const float*)d_in[8];
  const float* ln2b = (const float*)d_in[9];
  const float* Wv   = (const float*)d_in[10];
  const float* Wyin = (const float*)d_in[11];
  const float* Wy1  = (const float*)d_in[12];
  const float* by1  = (const float*)d_in[13];
  const float* Wy2  = (const float*)d_in[14];
  const float* by2  = (const float*)d_in[15];
  const float* Wxin = (const float*)d_in[16];
  const float* Wx1  = (const float*)d_in[17];
  const float* bx1  = (const float*)d_in[18];
  const float* Wx2  = (const float*)d_in[19];
  const float* bx2  = (const float*)d_in[20];
  const float* Wqkx = (const float*)d_in[21];
  const float* Wqky = (const float*)d_in[22];
  const float* Wm   = (const float*)d_in[23];
  const float* bm   = (const float*)d_in[24];
  const float* Wf1  = (const float*)d_in[25];
  const float* bf1  = (const float*)d_in[26];
  const float* Wf2  = (const float*)d_in[27];
  const float* bf2  = (const float*)d_in[28];

  char* w = (char*)d_ws;
  auto alloc = [&](size_t n) -> void* {
    void* p = (void*)w;
    w += (n + 255) & ~(size_t)255;
    return p;
  };
  bf16_t* UN   = (bf16_t*)alloc((size_t)NPOS*DIM*2);               // 32 MiB
  bf16_t* PHI  = (bf16_t*)alloc((size_t)NB*NH*NY*NX*DH_*2);        // 64 MiB
  float* POOLY = (float*)alloc((size_t)NB*NY*DIM*4);
  float* POOLX = (float*)alloc((size_t)NB*NX*DIM*4);
  float* TY    = (float*)alloc((size_t)512*256*4);
  float* TX    = (float*)alloc((size_t)512*256*4);
  float* HY    = (float*)alloc((size_t)512*1024*4);
  float* HX    = (float*)alloc((size_t)512*1024*4);
  float* UY    = (float*)alloc((size_t)512*256*4);
  float* UX    = (float*)alloc((size_t)512*256*4);
  float* QKY   = (float*)alloc((size_t)512*1024*4);
  float* QKX   = (float*)alloc((size_t)512*1024*4);
  float* QRY   = (float*)alloc((size_t)NB*NH*128*64*4);
  float* KRY   = (float*)alloc((size_t)NB*NH*128*64*4);
  float* QRX   = (float*)alloc((size_t)NB*NH*128*64*4);
  float* KRX   = (float*)alloc((size_t)NB*NH*128*64*4);
  bf16_t* ATTNY = (bf16_t*)alloc((size_t)NB*NH*128*128*2);
  bf16_t* ATTNX = (bf16_t*)alloc((size_t)NB*NH*128*128*2);
  short* WF1P  = (short*)alloc((size_t)256*1024*2);
  short* WF2P  = (short*)alloc((size_t)1024*256*2);
  short* WMP   = (short*)alloc((size_t)512*256*2);
  short* WVP   = (short*)alloc((size_t)256*512*2);
  short* WYINP = (short*)alloc((size_t)256*256*2);
  short* WY1P  = (short*)alloc((size_t)256*1024*2);
  short* WY2P  = (short*)alloc((size_t)1024*256*2);
  short* WQKYP = (short*)alloc((size_t)256*1024*2);
  short* WXINP = (short*)alloc((size_t)256*256*2);
  short* WX1P  = (short*)alloc((size_t)256*1024*2);
  short* WX2P  = (short*)alloc((size_t)1024*256*2);
  short* WQKXP = (short*)alloc((size_t)256*1024*2);
  float* U2 = (float*)d_out;
  (void)in_sizes; (void)n_in; (void)out_size; (void)ws_size;

  // ---- all weight packs in one launch
  PackArgs pa;
  const float* srcs[12] = {Wf1,Wf2,Wm,Wv,Wyin,Wy1,Wy2,Wqky,Wxin,Wx1,Wx2,Wqkx};
  short* dsts[12] = {WF1P,WF2P,WMP,WVP,WYINP,WY1P,WY2P,WQKYP,WXINP,WX1P,WX2P,WQKXP};
  int Ks[12] = {256,1024,512,256,256,256,1024,256,256,256,1024,256};
  int Ns[12] = {1024,256,256,512,256,1024,256,1024,256,1024,256,1024};
  int boffs[12] = {0,128,256,320,384,416,544,672,800,832,960,1088};
  for (int i=0;i<12;i++){
    pa.src[i]=srcs[i]; pa.dst[i]=dsts[i]; pa.K[i]=Ks[i]; pa.N[i]=Ns[i]; pa.boff[i]=boffs[i];
  }
  k_pack_all<<<1216, 256, 0, stream>>>(pa);

  k_ln1<<<NPOS/4, 256, 0, stream>>>(u, ln1g, ln1b, UN);
  k_pool_y<<<NB*NY, 1024, 0, stream>>>(UN, POOLY);
  k_pool_x<<<NB*NX, 1024, 0, stream>>>(UN, POOLX);

  // x/y chains fused via grid.z: pool -> Win -> gelu-MLP -> QK
  k_gemm2<<<dim3(8,1,2), 256, 0, stream>>>(POOLY, POOLX, WYINP, WXINP,
      (const float*)nullptr, (const float*)nullptr, TY, TX, 256, 256, 0);
  k_gemm2<<<dim3(8,4,2), 256, 0, stream>>>(TY, TX, WY1P, WX1P, by1, bx1, HY, HX, 1024, 256, 1);
  k_gemm2<<<dim3(8,1,2), 256, 0, stream>>>(HY, HX, WY2P, WX2P, by2, bx2, UY, UX, 256, 1024, 0);
  k_gemm2<<<dim3(8,4,2), 256, 0, stream>>>(UY, UX, WQKYP, WQKXP,
      (const float*)nullptr, (const float*)nullptr, QKY, QKX, 1024, 256, 0);

  k_rope2<<<dim3((NB*128*1024)/256, 2), 256, 0, stream>>>(QKY, QKX,
      rcy, rsy, rcx, rsx, QRY, KRY, QRX, KRX);
  k_attn2<<<dim3(NB*NH*128, 2), 128, 0, stream>>>(QRY, KRY, ATTNY, QRX, KRX, ATTNX);
  k_phi1m<<<NB*NH*NX, 512, 0, stream>>>(UN, WVP, ATTNY, PHI);
  k_phi2m<<<NB*NH*NY, 512, 0, stream>>>(ATTNX, PHI);
  k_tail<<<NPOS/64, 512, 0, stream>>>(PHI, WMP, bm, u, ln2g, ln2b,
      WF1P, bf1, WF2P, bf2, U2);
}